// Round 1
// baseline (375.299 us; speedup 1.0000x reference)
//
#include <hip/hip_runtime.h>
#include <math.h>

#define A_TOT   10647
#define BATCH   64
#define NTGT    50
#define NC      80
#define MAXREC  64          // slots per batch (<= NTGT distinct cells possible)
#define TOT_CELLS (BATCH * A_TOT)

struct Rec {
    int cell;
    float tx, ty, tw, th, wwh, tconf;
    unsigned c0, c1, c2;    // 80-bit class set
};  // 40 bytes

// ---------------------------------------------------------------------------
// Phase A: per-target anchor matching, noobj hit clearing, deduped scatter
// records with last-write-wins semantics (matches numpy fancy assignment).
// One block per batch; threads 0..49 process targets in parallel, thread 0
// merges serially in n-order for deterministic duplicate resolution.
// ---------------------------------------------------------------------------
__global__ __launch_bounds__(64) void phaseA(const float* __restrict__ tgt,
                                             unsigned char* __restrict__ noobj,
                                             int* __restrict__ counts,
                                             Rec* __restrict__ recs) {
    __shared__ int   s_valid[64];
    __shared__ int   s_idx[64];
    __shared__ float s_tx[64], s_ty[64], s_tw[64], s_th[64], s_wwh[64], s_tc[64];
    __shared__ int   s_cls[64];
    __shared__ Rec   s_rec[NTGT];
    __shared__ int   s_cnt;

    const int b = blockIdx.x;
    const int n = threadIdx.x;

    const float fs[3] = {13.f, 26.f, 52.f};
    const int   ln[3] = {0, 507, 2535};
    // SCALED_ANCHORS[m][k] = ANCHORS[m][k] / stride_m
    const float aw[3][3] = {{3.625f, 4.875f, 11.65625f},
                            {1.875f, 3.875f, 3.6875f},
                            {1.25f,  2.0f,   4.125f}};
    const float ah[3][3] = {{2.8125f, 6.1875f, 10.1875f},
                            {3.8125f, 2.8125f, 7.4375f},
                            {1.625f,  3.75f,   2.875f}};

    int valid = 0;
    if (n < NTGT) {
        const float* t = tgt + (size_t)(b * NTGT + n) * 5;
        float t0 = t[0], t1 = t[1], t2 = t[2], t3 = t[3], t4 = t[4];
        valid = ((t0 + t1 + t2 + t3 + t4) != 0.0f);
        if (valid) {
            float best_m_iou = -1.f;
            int bf = 0, best_a = 0, gi_b = 0, gj_b = 0;
            for (int m = 0; m < 3; m++) {
                float gw = t3 * fs[m], gh = t4 * fs[m];
                int gi = (int)floorf(t1 * fs[m]);
                int gj = (int)floorf(t2 * fs[m]);
                float bi = -1.f; int bk = 0;
                for (int k = 0; k < 3; k++) {
                    float in_ = fminf(gw, aw[m][k]) * fminf(gh, ah[m][k]);
                    float un  = gw * gh + aw[m][k] * ah[m][k] - in_;
                    float iou = in_ / (un + 1e-16f);
                    if (iou > bi) { bi = iou; bk = k; }       // first-max (argmax)
                    if (iou > 0.5f)                            // IGNORE_THR hit
                        noobj[(size_t)b * A_TOT + ln[m] + 3 * gi * gj + k] = 0;
                }
                if (bi > best_m_iou) { best_m_iou = bi; bf = m; best_a = bk; gi_b = gi; gj_b = gj; }
            }
            s_idx[n] = ln[bf] + 3 * gi_b * gj_b + best_a;
            s_tx[n]  = t1 * 416.f;
            s_ty[n]  = t2 * 416.f;
            s_tw[n]  = t3 * 416.f;
            s_th[n]  = t4 * 416.f;
            s_wwh[n] = 2.0f - t3 * t4;
            s_tc[n]  = best_m_iou;
            s_cls[n] = (int)t0;
        }
    }
    s_valid[n] = valid;
    __syncthreads();

    if (threadIdx.x == 0) {
        int cnt = 0;
        for (int i = 0; i < NTGT; i++) {
            if (!s_valid[i]) continue;
            int cell = s_idx[i];
            int j = -1;
            for (int q = 0; q < cnt; q++)
                if (s_rec[q].cell == cell) { j = q; break; }
            if (j < 0) {
                j = cnt++;
                s_rec[j].cell = cell;
                s_rec[j].c0 = 0u; s_rec[j].c1 = 0u; s_rec[j].c2 = 0u;
            }
            // last write wins for scalar fields
            s_rec[j].tx = s_tx[i];  s_rec[j].ty = s_ty[i];
            s_rec[j].tw = s_tw[i];  s_rec[j].th = s_th[i];
            s_rec[j].wwh = s_wwh[i]; s_rec[j].tconf = s_tc[i];
            // class bits are a union across all targets hitting the cell
            int c = s_cls[i];
            if (c < 32)       s_rec[j].c0 |= 1u << c;
            else if (c < 64)  s_rec[j].c1 |= 1u << (c - 32);
            else              s_rec[j].c2 |= 1u << (c - 64);
        }
        s_cnt = cnt;
        counts[b] = cnt;
    }
    __syncthreads();
    int cnt = s_cnt;
    for (int r = threadIdx.x; r < cnt; r += 64)
        recs[b * MAXREC + r] = s_rec[r];
}

// ---------------------------------------------------------------------------
// K2: sum of -log(1 - conf) over cells with noobj==1 (the only dense term).
// ---------------------------------------------------------------------------
__global__ __launch_bounds__(256) void noobjSum(const float* __restrict__ pred,
                                                const unsigned char* __restrict__ noobj,
                                                double* __restrict__ sums) {
    double s = 0.0;
    for (int id = blockIdx.x * blockDim.x + threadIdx.x; id < TOT_CELLS;
         id += gridDim.x * blockDim.x) {
        if (noobj[id]) {
            float conf = pred[(size_t)id * 85 + 4];
            s -= (double)logf(1.0f - conf);
        }
    }
    for (int off = 32; off; off >>= 1) s += __shfl_down(s, off, 64);
    __shared__ double w_[4];
    int lane = threadIdx.x & 63, w = threadIdx.x >> 6;
    if (lane == 0) w_[w] = s;
    __syncthreads();
    if (threadIdx.x == 0) {
        double t = w_[0] + w_[1] + w_[2] + w_[3];
        atomicAdd(&sums[1], t);
    }
}

// ---------------------------------------------------------------------------
// K3: per-record terms — xywh MSE, conf BCE (masked), and 80-class BCE.
// One block per batch.
// ---------------------------------------------------------------------------
__global__ __launch_bounds__(256) void recTerms(const float* __restrict__ pred,
                                                const int* __restrict__ counts,
                                                const Rec* __restrict__ recs,
                                                double* __restrict__ sums) {
    const int b = blockIdx.x;
    const int cnt = counts[b];
    __shared__ Rec s_rec[MAXREC];
    for (int r = threadIdx.x; r < cnt; r += blockDim.x)
        s_rec[r] = recs[b * MAXREC + r];
    __syncthreads();

    double sA = 0.0;   // xywh + conf-term-1, denominator B*A
    double sC = 0.0;   // cls,               denominator npos*NC

    for (int r = threadIdx.x; r < cnt; r += blockDim.x) {
        const Rec& rec = s_rec[r];
        const float* p = pred + ((size_t)b * A_TOT + rec.cell) * 85;
        float x = p[0], y = p[1], w = p[2], h = p[3], conf = p[4];
        float wwh = rec.wwh;
        float dx = x * wwh - rec.tx * wwh;
        float dy = y * wwh - rec.ty * wwh;
        float dw = w * wwh - rec.tw * wwh;
        float dh = h * wwh - rec.th * wwh;
        sA += (double)(dx * dx) + (double)(dy * dy) +
              (double)(dw * dw) + (double)(dh * dh);
        float t = rec.tconf;
        sA -= (double)(t * logf(conf) + (1.0f - t) * logf(1.0f - conf));
    }

    for (int q = threadIdx.x; q < cnt * NC; q += blockDim.x) {
        int r = q / NC, c = q - r * NC;
        const Rec& rec = s_rec[r];
        const float* p = pred + ((size_t)b * A_TOT + rec.cell) * 85 + 5;
        float pc = p[c];
        unsigned bit;
        if (c < 32)       bit = (rec.c0 >> c) & 1u;
        else if (c < 64)  bit = (rec.c1 >> (c - 32)) & 1u;
        else              bit = (rec.c2 >> (c - 64)) & 1u;
        sC -= bit ? (double)logf(pc) : (double)logf(1.0f - pc);
    }

    for (int off = 32; off; off >>= 1) {
        sA += __shfl_down(sA, off, 64);
        sC += __shfl_down(sC, off, 64);
    }
    __shared__ double wA[4], wC[4];
    int lane = threadIdx.x & 63, w = threadIdx.x >> 6;
    if (lane == 0) { wA[w] = sA; wC[w] = sC; }
    __syncthreads();
    if (threadIdx.x == 0) {
        atomicAdd(&sums[0], wA[0] + wA[1] + wA[2] + wA[3]);
        atomicAdd(&sums[2], wC[0] + wC[1] + wC[2] + wC[3]);
    }
}

// ---------------------------------------------------------------------------
// K4: combine.
// ---------------------------------------------------------------------------
__global__ void finalK(const double* __restrict__ sums,
                       const int* __restrict__ counts,
                       float* __restrict__ out) {
    if (blockIdx.x == 0 && threadIdx.x == 0) {
        int npos = 0;
        for (int i = 0; i < BATCH; i++) npos += counts[i];
        double total = (sums[0] + 0.5 * sums[1]) / (double)TOT_CELLS;
        if (npos > 0) total += sums[2] / ((double)npos * (double)NC);
        out[0] = (float)total;
    }
}

extern "C" void kernel_launch(void* const* d_in, const int* in_sizes, int n_in,
                              void* d_out, int out_size, void* d_ws, size_t ws_size,
                              hipStream_t stream) {
    const float* pred = (const float*)d_in[0];   // (64, 10647, 85) f32
    const float* tgt  = (const float*)d_in[1];   // (64, 50, 5) f32
    // d_in[2] = stride (always 32; fsizes/last_num hardcoded accordingly)

    char* ws = (char*)d_ws;
    double*        sums   = (double*)ws;                  // [0..32)   3 doubles used
    int*           counts = (int*)(ws + 32);              // [32..288) 64 ints
    Rec*           recs   = (Rec*)(ws + 512);             // 64*64*40 = 163840 B
    unsigned char* noobj  = (unsigned char*)(ws + 165376);// 681408 B  (~846 KB total)

    hipMemsetAsync(sums, 0, 4 * sizeof(double), stream);
    hipMemsetAsync(noobj, 1, TOT_CELLS, stream);

    phaseA<<<BATCH, 64, 0, stream>>>(tgt, noobj, counts, recs);
    noobjSum<<<(TOT_CELLS + 255) / 256, 256, 0, stream>>>(pred, noobj, sums);
    recTerms<<<BATCH, 256, 0, stream>>>(pred, counts, recs, sums);
    finalK<<<1, 64, 0, stream>>>(sums, counts, (float*)d_out);
}